// Round 3
// baseline (210.879 us; speedup 1.0000x reference)
//
#include <hip/hip_runtime.h>
#include <hip/hip_bf16.h>
#include <stdint.h>

// GPTQ int4 linear via bf16 MFMA. M=32, K=8192, N=8192, group=64.
// R12: BN=128/KSPLIT=8 kept (xb traffic 64->32 MB, total vmem 200->172 MB)
// but pipeline register footprint halved vs R11: pb[2][8] + xa[2][2],
// prefetch distance 1. R11's miss (main ~46us vs 37.6 model) diagnosed as
// VGPR spill: acc64 + pb96 + xa24 + ptrs16 + temps > 256 cap -> scratch
// traffic at the same ~4.5 TB/s effective rate. New static count ~185.
// Model (validated exactly by R10): main_us = vmem_MB / 4.57; fills 156us
// are unconditional harness re-poison and untouchable.
// LDS: red[4][32][132]=67.6KB unioned over scz (dead after loop), 2 blk/CU.

#define KK 8192
#define NN 8192
#define KP 4096      // int32 per weight row
#define NG 128       // quant groups per row
#define BN 128       // n per block
#define KSPLIT 8
#define KSPW 8       // ksteps (32 k each) per wave
#define NKS 256      // total ksteps

typedef __attribute__((ext_vector_type(8))) short short8;
typedef __attribute__((ext_vector_type(4))) float floatx4;
typedef __attribute__((ext_vector_type(4))) int int4v;

__device__ __forceinline__ unsigned pack_bf16x2(float lo, float hi) {
    union { __hip_bfloat162 h; unsigned u; } c;
    c.h = __float22bfloat162_rn(make_float2(lo, hi));
    return c.u;
}

// dequant 2 nibbles -> packed bf16x2 (RNE; w finite, no NaN path)
__device__ __forceinline__ unsigned dq2(int q, float sc, float zs) {
    float lo = fmaf((float)(q & 15),        sc, zs);
    float hi = fmaf((float)((q >> 4) & 15), sc, zs);
    unsigned ua = __float_as_uint(lo); ua += 0x7fffu + ((ua >> 16) & 1u);
    unsigned ub = __float_as_uint(hi); ub += 0x7fffu + ((ub >> 16) & 1u);
    return __builtin_amdgcn_perm(ub, ua, 0x07060302);   // [ub.hi16 : ua.hi16]
}

// blocks [0,xconv_blocks): x fp32 -> bf16 A-frags in xb; rest: out = bias.
__global__ void prep_kernel(const float* __restrict__ x, const float* __restrict__ bias,
                            ushort* __restrict__ xb, float* __restrict__ out,
                            int xconv_blocks)
{
    const int bx = blockIdx.x;
    if (bx < xconv_blocks) {
        const int tid = bx * 256 + threadIdx.x;   // 0..32767
        const int l   = tid & 63;
        const int ks  = (tid >> 6) & 255;
        const int mt  = tid >> 14;
        const int m   = (l & 15) + 16 * mt;
        const int kb  = ks * 32 + (l >> 4) * 8;
        const float* src = x + (size_t)m * KK + kb;
        const float4 a = *(const float4*)(src);
        const float4 b = *(const float4*)(src + 4);
        *(uint4*)(xb + (size_t)tid * 8) =
            make_uint4(pack_bf16x2(a.x, a.y), pack_bf16x2(a.z, a.w),
                       pack_bf16x2(b.x, b.y), pack_bf16x2(b.z, b.w));
    } else {
        const int f4 = (bx - xconv_blocks) * 256 + threadIdx.x;  // 0..65535
        const int n4 = f4 & (NN / 4 - 1);
        ((float4*)out)[f4] = ((const float4*)bias)[n4];
    }
}

__global__ __launch_bounds__(256, 2)
void gptq_mfma_main(const int*   __restrict__ pw,
                    const float* __restrict__ scales,
                    const float* __restrict__ zeros,
                    const ushort* __restrict__ xb,
                    float* __restrict__ out)
{
    // Union LDS: scz ([16][132] x2, 16.9 KB) lives during the loop;
    // red ([4][32][132], 67.6 KB) overwrites it after a barrier.
    __shared__ __align__(16) float smem[4 * 32 * 132];   // 67584 B
    float (*sc_lds)[132] = (float (*)[132])smem;               // [16][132]
    float (*zs_lds)[132] = (float (*)[132])(smem + 16 * 132);  // [16][132]
    float (*red)[32][132] = (float (*)[32][132])smem;          // [4][32][132]

    const int tid  = threadIdx.x;
    const int lane = tid & 63;
    const int wave = tid >> 6;
    const int kh   = blockIdx.x & (KSPLIT - 1);
    const int n0   = (blockIdx.x >> 3) * BN;
    const int nl   = lane & 15;     // B-frag col within 16-n frag
    const int kq   = lane >> 4;     // k-quad
    const int ks0  = kh * 32 + wave * KSPW;   // global kstep base for this wave

    // ---- stage scales/zeros for 128 rows x 16 groups; zs = -z*s ----
    {
        const int r  = tid >> 1;          // n_local 0..127
        const int go = (tid & 1) * 8;     // group_local base 0 or 8
        const float* sp = scales + (size_t)(n0 + r) * NG + kh * 16 + go;
        const float* zp = zeros  + (size_t)(n0 + r) * NG + kh * 16 + go;
#pragma unroll
        for (int t = 0; t < 2; ++t) {
            const float4 s4 = *(const float4*)(sp + t * 4);
            const float4 z4 = *(const float4*)(zp + t * 4);
            sc_lds[go + t*4 + 0][r] = s4.x; zs_lds[go + t*4 + 0][r] = -z4.x * s4.x;
            sc_lds[go + t*4 + 1][r] = s4.y; zs_lds[go + t*4 + 1][r] = -z4.y * s4.y;
            sc_lds[go + t*4 + 2][r] = s4.z; zs_lds[go + t*4 + 2][r] = -z4.z * s4.z;
            sc_lds[go + t*4 + 3][r] = s4.w; zs_lds[go + t*4 + 3][r] = -z4.w * s4.w;
        }
    }
    __syncthreads();

    // ---- pw pointers: 8 weight-row streams per lane (rows nl + 16f) ----
    const int* pwp[8];
#pragma unroll
    for (int f = 0; f < 8; ++f)
        pwp[f] = pw + (size_t)(n0 + f * 16 + nl) * KP + kq * 4;
    const uint4* xfp = (const uint4*)xb;

    floatx4 acc[8][2];
#pragma unroll
    for (int f = 0; f < 8; ++f)
#pragma unroll
        for (int mt = 0; mt < 2; ++mt)
            acc[f][mt] = (floatx4){0.f, 0.f, 0.f, 0.f};

    int4v pb[2][8];    // [slot][frag], 2 slots, prefetch distance 1
    uint4 xa[2][2];    // [slot][mt]

    // prologue: 1 kstep
    {
        const int ks = ks0;
#pragma unroll
        for (int f = 0; f < 8; ++f)
            pb[0][f] = *(const int4v*)(pwp[f] + ks * 16);
        xa[0][0] = xfp[(size_t)(0 * NKS + ks) * 64 + lane];
        xa[0][1] = xfp[(size_t)(1 * NKS + ks) * 64 + lane];
    }

#pragma unroll
    for (int i = 0; i < KSPW; ++i) {
        const int slot = i & 1;
        if (i + 1 < KSPW) {
            const int ks = ks0 + i + 1;
            const int ps = slot ^ 1;
#pragma unroll
            for (int f = 0; f < 8; ++f)
                pb[ps][f] = *(const int4v*)(pwp[f] + ks * 16);
            xa[ps][0] = xfp[(size_t)(0 * NKS + ks) * 64 + lane];
            xa[ps][1] = xfp[(size_t)(1 * NKS + ks) * 64 + lane];
        }
        const int gl = (wave * KSPW + i) >> 1;   // group local to block

        union { uint4 v; short8 sv; } a0, a1;
        a0.v = xa[slot][0];
        a1.v = xa[slot][1];
#pragma unroll
        for (int f = 0; f < 8; ++f) {
            const float sc = sc_lds[gl][f * 16 + nl];
            const float zs = zs_lds[gl][f * 16 + nl];
            union { uint4 v; short8 sv; } bf;
            const int4v p = pb[slot][f];
            bf.v.x = dq2(p.x, sc, zs);
            bf.v.y = dq2(p.y, sc, zs);
            bf.v.z = dq2(p.z, sc, zs);
            bf.v.w = dq2(p.w, sc, zs);
            acc[f][0] = __builtin_amdgcn_mfma_f32_16x16x32_bf16(a0.sv, bf.sv, acc[f][0], 0, 0, 0);
            acc[f][1] = __builtin_amdgcn_mfma_f32_16x16x32_bf16(a1.sv, bf.sv, acc[f][1], 0, 0, 0);
        }
    }

    // scz is dead from here; barrier before red overwrites the same LDS.
    __syncthreads();

    // ---- epilogue: 4-wave (K-split within block) LDS reduce, then atomicAdd ----
#pragma unroll
    for (int f = 0; f < 8; ++f)
#pragma unroll
        for (int mt = 0; mt < 2; ++mt)
#pragma unroll
            for (int r = 0; r < 4; ++r)
                red[wave][mt * 16 + kq * 4 + r][f * 16 + nl] = acc[f][mt][r];
    __syncthreads();

#pragma unroll
    for (int j = 0; j < 16; ++j) {
        const int e = j * 256 + tid;      // 0..4095 partial elems
        const int m = e >> 7, c = e & 127;
        const float s = red[0][m][c] + red[1][m][c] + red[2][m][c] + red[3][m][c];
        atomicAdd(out + (size_t)m * NN + n0 + c, s);
    }
}

// Fallback (no workspace): register-path kernel, direct fp32 x loads, atomics.
__global__ __launch_bounds__(256, 4)
void gptq_mfma_fallback(const int*   __restrict__ pw,
                        const float* __restrict__ scales,
                        const float* __restrict__ zeros,
                        const float* __restrict__ x,
                        float* __restrict__ out)
{
    __shared__ float s_lds[64][17];
    __shared__ float z_lds[64][17];
    __shared__ float red[4][2][256];

    const int tid  = threadIdx.x;
    const int lane = tid & 63;
    const int wave = tid >> 6;
    const int kh   = blockIdx.x & 1;
    const int n0   = (blockIdx.x >> 1) * 16;
    const int g0   = kh * 64;

    {
        const int r  = tid >> 4;
        const int gb = (tid & 15) * 4;
        const float4 s4 = *(const float4*)(scales + (size_t)(n0 + r) * NG + g0 + gb);
        const float4 z4 = *(const float4*)(zeros  + (size_t)(n0 + r) * NG + g0 + gb);
        s_lds[gb + 0][r] = s4.x; s_lds[gb + 1][r] = s4.y;
        s_lds[gb + 2][r] = s4.z; s_lds[gb + 3][r] = s4.w;
        z_lds[gb + 0][r] = z4.x; z_lds[gb + 1][r] = z4.y;
        z_lds[gb + 2][r] = z4.z; z_lds[gb + 3][r] = z4.w;
    }
    __syncthreads();

    const int nl = lane & 15;
    const int kq = lane >> 4;
    const int* pwp = pw + (size_t)(n0 + nl) * KP + kq * 4;
    const int ks0 = kh * 128 + wave * 32;

    auto load_xfrag = [&](int mt, int ks) -> uint4 {
        const float* src = x + (size_t)(nl + 16 * mt) * KK + ks * 32 + kq * 8;
        const float4 a = *(const float4*)(src);
        const float4 b = *(const float4*)(src + 4);
        return make_uint4(pack_bf16x2(a.x, a.y), pack_bf16x2(a.z, a.w),
                          pack_bf16x2(b.x, b.y), pack_bf16x2(b.z, b.w));
    };

    floatx4 acc0 = {0.f, 0.f, 0.f, 0.f};
    floatx4 acc1 = {0.f, 0.f, 0.f, 0.f};
    int4v pwb[4];
    uint4 x0b[4], x1b[4];

#pragma unroll
    for (int i = 0; i < 3; ++i) {
        const int ks = ks0 + i;
        pwb[i] = *(const int4v*)(pwp + ks * 16);
        x0b[i] = load_xfrag(0, ks);
        x1b[i] = load_xfrag(1, ks);
    }

#pragma unroll 4
    for (int i = 0; i < 32; ++i) {
        const int slot = i & 3;
        if (i + 3 < 32) {
            const int ks = ks0 + i + 3;
            const int ps = (i + 3) & 3;
            pwb[ps] = *(const int4v*)(pwp + ks * 16);
            x0b[ps] = load_xfrag(0, ks);
            x1b[ps] = load_xfrag(1, ks);
        }
        const int gl  = (wave * 32 + i) >> 1;
        const float sc = s_lds[gl][nl];
        const float zs = -z_lds[gl][nl] * sc;

        union { uint4 v; short8 sv; } bf, a0, a1;
        const int4v p = pwb[slot];
        bf.v.x = dq2(p.x, sc, zs);
        bf.v.y = dq2(p.y, sc, zs);
        bf.v.z = dq2(p.z, sc, zs);
        bf.v.w = dq2(p.w, sc, zs);
        a0.v = x0b[slot];
        a1.v = x1b[slot];
        acc0 = __builtin_amdgcn_mfma_f32_16x16x32_bf16(a0.sv, bf.sv, acc0, 0, 0, 0);
        acc1 = __builtin_amdgcn_mfma_f32_16x16x32_bf16(a1.sv, bf.sv, acc1, 0, 0, 0);
    }

#pragma unroll
    for (int r = 0; r < 4; ++r) {
        const int row = kq * 4 + r;
        red[wave][0][row * 16 + nl] = acc0[r];
        red[wave][1][row * 16 + nl] = acc1[r];
    }
    __syncthreads();

#pragma unroll
    for (int i = 0; i < 2; ++i) {
        const int e   = i * 256 + tid;
        const int mt  = e >> 8;
        const int idx = e & 255;
        const float s = red[0][mt][idx] + red[1][mt][idx] + red[2][mt][idx] + red[3][mt][idx];
        atomicAdd(out + (size_t)(mt * 16 + (idx >> 4)) * NN + n0 + (idx & 15), s);
    }
}

extern "C" void kernel_launch(void* const* d_in, const int* in_sizes, int n_in,
                              void* d_out, int out_size, void* d_ws, size_t ws_size,
                              hipStream_t stream) {
    const float* x      = (const float*)d_in[0];
    const int*   pw     = (const int*)  d_in[1];
    const float* scales = (const float*)d_in[2];
    const float* zeros  = (const float*)d_in[3];
    const float* bias   = (const float*)d_in[4];
    float* out = (float*)d_out;

    const size_t need = (size_t)32768 * 16;   // 512 KB of bf16 A-frags
    if (d_ws != nullptr && ws_size >= need) {
        ushort* xb = (ushort*)d_ws;
        prep_kernel<<<128 + 256, 256, 0, stream>>>(x, bias, xb, out, 128);
        gptq_mfma_main<<<(NN / BN) * KSPLIT, 256, 0, stream>>>(pw, scales, zeros, xb, out);
    } else {
        prep_kernel<<<256, 256, 0, stream>>>(x, bias, nullptr, out, 0);
        gptq_mfma_fallback<<<1024, 256, 0, stream>>>(pw, scales, zeros, x, out);
    }
}

// Round 4
// 207.802 us; speedup vs baseline: 1.0148x; 1.0148x over previous
//
#include <hip/hip_runtime.h>
#include <hip/hip_bf16.h>
#include <stdint.h>

// GPTQ int4 linear via bf16 MFMA. M=32, K=8192, N=8192, group=64.
// R13: pw DRAM-granularity fix. R9/R11/R12 invariance (208.9/210.8/210.9
// despite -28 MB traffic and -40 VGPR) proves main is NOT total-byte-bound;
// the invariant is pw's 64 B/row/kstep access granularity (16 discrete 64 B
// segments per wave-inst at 16 KB stride) -> effective ~3.5 TB/s, pw-bound
// ~40 us. Fix: stage pw via global_load_lds in 256 B-contiguous row chunks
// (4 ksteps/round, 32 KB tile, double-buffered); waves split K interleaved
// (wave w does kstep 4r+w) so all consume the same tile. XOR-swizzle
// (o ^= (row&7)<<4) applied to the per-lane GLOBAL source (LDS dest linear,
// G21) and to the ds_read addr -> 2-way conflicts only.
// LDS: pwbuf 64K + sc/zs 16K = 80 KB exactly (2 blk/CU); red overlays after
// final barrier. Fills (2x512 MiB, 156 us) are harness re-poison, fixed.

#define KK 8192
#define NN 8192
#define KP 4096      // int32 per weight row
#define NG 128       // quant groups per row
#define BN 128       // n per block
#define KSPLIT 8
#define NKS 256      // total ksteps
#define ROUNDS 8     // 32 block-ksteps / 4 per round

typedef __attribute__((ext_vector_type(8))) short short8;
typedef __attribute__((ext_vector_type(4))) float floatx4;
typedef __attribute__((ext_vector_type(4))) int int4v;

__device__ __forceinline__ unsigned pack_bf16x2(float lo, float hi) {
    union { __hip_bfloat162 h; unsigned u; } c;
    c.h = __float22bfloat162_rn(make_float2(lo, hi));
    return c.u;
}

// dequant 2 nibbles -> packed bf16x2 (RNE; w finite, no NaN path)
__device__ __forceinline__ unsigned dq2(int q, float sc, float zs) {
    float lo = fmaf((float)(q & 15),        sc, zs);
    float hi = fmaf((float)((q >> 4) & 15), sc, zs);
    unsigned ua = __float_as_uint(lo); ua += 0x7fffu + ((ua >> 16) & 1u);
    unsigned ub = __float_as_uint(hi); ub += 0x7fffu + ((ub >> 16) & 1u);
    return __builtin_amdgcn_perm(ub, ua, 0x07060302);   // [ub.hi16 : ua.hi16]
}

__device__ __forceinline__ void gload_lds16(const void* g, void* l) {
    __builtin_amdgcn_global_load_lds(
        (const __attribute__((address_space(1))) unsigned int*)g,
        (__attribute__((address_space(3))) unsigned int*)l, 16, 0, 0);
}

// blocks [0,xconv_blocks): x fp32 -> bf16 A-frags in xb; rest: out = bias.
__global__ void prep_kernel(const float* __restrict__ x, const float* __restrict__ bias,
                            ushort* __restrict__ xb, float* __restrict__ out,
                            int xconv_blocks)
{
    const int bx = blockIdx.x;
    if (bx < xconv_blocks) {
        const int tid = bx * 256 + threadIdx.x;   // 0..32767
        const int l   = tid & 63;
        const int ks  = (tid >> 6) & 255;
        const int mt  = tid >> 14;
        const int m   = (l & 15) + 16 * mt;
        const int kb  = ks * 32 + (l >> 4) * 8;
        const float* src = x + (size_t)m * KK + kb;
        const float4 a = *(const float4*)(src);
        const float4 b = *(const float4*)(src + 4);
        *(uint4*)(xb + (size_t)tid * 8) =
            make_uint4(pack_bf16x2(a.x, a.y), pack_bf16x2(a.z, a.w),
                       pack_bf16x2(b.x, b.y), pack_bf16x2(b.z, b.w));
    } else {
        const int f4 = (bx - xconv_blocks) * 256 + threadIdx.x;  // 0..65535
        const int n4 = f4 & (NN / 4 - 1);
        ((float4*)out)[f4] = ((const float4*)bias)[n4];
    }
}

__global__ __launch_bounds__(256, 2)
void gptq_mfma_main(const int*   __restrict__ pw,
                    const float* __restrict__ scales,
                    const float* __restrict__ zeros,
                    const ushort* __restrict__ xb,
                    float* __restrict__ out)
{
    // LDS map (bytes):
    //   [0,65536)      pwbuf[2][128 rows][256 B]   (XOR-swizzled row chunks)
    //   [65536,73728)  sc[16][128]
    //   [73728,81920)  zs[16][128]   (zs = -z*s)
    //   red overlay float[4][32][132] at [0,67584) after final barrier
    __shared__ __align__(16) unsigned char smem[81920];
    float* sc_lds = (float*)(smem + 65536);
    float* zs_lds = (float*)(smem + 73728);
    float (*red)[32][132] = (float (*)[32][132])smem;

    const int tid  = threadIdx.x;
    const int lane = tid & 63;
    const int wave = tid >> 6;
    const int kh   = blockIdx.x & (KSPLIT - 1);
    const int n0   = (blockIdx.x >> 3) * BN;
    const int nl   = lane & 15;
    const int kq   = lane >> 4;

    // ---- stage scales/zeros for 128 rows x 16 groups; zs = -z*s ----
    {
        const int rr = tid >> 1;          // n_local 0..127
        const int go = (tid & 1) * 8;     // group_local base 0 or 8
        const float* sp = scales + (size_t)(n0 + rr) * NG + kh * 16 + go;
        const float* zp = zeros  + (size_t)(n0 + rr) * NG + kh * 16 + go;
#pragma unroll
        for (int t = 0; t < 2; ++t) {
            const float4 s4 = *(const float4*)(sp + t * 4);
            const float4 z4 = *(const float4*)(zp + t * 4);
            sc_lds[(go + t*4 + 0)*128 + rr] = s4.x; zs_lds[(go + t*4 + 0)*128 + rr] = -z4.x * s4.x;
            sc_lds[(go + t*4 + 1)*128 + rr] = s4.y; zs_lds[(go + t*4 + 1)*128 + rr] = -z4.y * s4.y;
            sc_lds[(go + t*4 + 2)*128 + rr] = s4.z; zs_lds[(go + t*4 + 2)*128 + rr] = -z4.z * s4.z;
            sc_lds[(go + t*4 + 3)*128 + rr] = s4.w; zs_lds[(go + t*4 + 3)*128 + rr] = -z4.w * s4.w;
        }
    }

    // ---- pw stage source pointers: wave w stages rows 32w..32w+31 ----
    // Inst i covers rows 32w+4i..+3 (lane>>4 selects row, lane&15 the 16 B).
    // Source pre-swizzled: o = (nl*16) ^ ((row&7)<<4)  (LDS dest is linear).
    const unsigned char* gsrc[8];
    {
        const unsigned char* pwB = (const unsigned char*)pw + (size_t)kh * 2048;
#pragma unroll
        for (int i = 0; i < 8; ++i) {
            const int rl = 32 * wave + 4 * i + kq;          // row local 0..127
            const int o  = (nl * 16) ^ ((rl & 7) << 4);
            gsrc[i] = pwB + (size_t)(n0 + rl) * 16384 + o;
        }
    }

    // ---- prologue: stage round 0 into buf0; prefetch xa for round 0 ----
    {
        unsigned char* dst = smem + wave * 8192;
#pragma unroll
        for (int i = 0; i < 8; ++i)
            gload_lds16(gsrc[i], dst + i * 1024);
    }
    const uint4* xfp = (const uint4*)xb;
    uint4 xa[2][2];
    {
        const int ks = kh * 32 + wave;      // round 0 kstep for this wave
        xa[0][0] = xfp[(size_t)(0 * NKS + ks) * 64 + lane];
        xa[0][1] = xfp[(size_t)(1 * NKS + ks) * 64 + lane];
    }

    floatx4 acc[8][2];
#pragma unroll
    for (int f = 0; f < 8; ++f)
#pragma unroll
        for (int mt = 0; mt < 2; ++mt)
            acc[f][mt] = (floatx4){0.f, 0.f, 0.f, 0.f};

    __syncthreads();   // drains stage(0) + scz writes + xa prefetch

#pragma unroll
    for (int r = 0; r < ROUNDS; ++r) {
        // issue next-round staging first (in flight across this round's compute)
        if (r + 1 < ROUNDS) {
            unsigned char* dst = smem + ((r + 1) & 1) * 32768 + wave * 8192;
#pragma unroll
            for (int i = 0; i < 8; ++i)
                gload_lds16(gsrc[i] + (size_t)(r + 1) * 256, dst + i * 1024);
            // xa prefetch for next round (drained by this round's barrier)
            const int ksn = kh * 32 + (r + 1) * 4 + wave;
            xa[(r + 1) & 1][0] = xfp[(size_t)(0 * NKS + ksn) * 64 + lane];
            xa[(r + 1) & 1][1] = xfp[(size_t)(1 * NKS + ksn) * 64 + lane];
        }

        // ---- compute this wave's kstep (4r + wave) from buf[r&1] ----
        const int gl = (r * 4 + wave) >> 1;     // block-local group
        const unsigned char* pwb = smem + (r & 1) * 32768;
        const int boff = nl * 256 + ((wave * 64 + kq * 16) ^ ((nl & 7) << 4));

        union { uint4 v; short8 sv; } a0, a1;
        a0.v = xa[r & 1][0];
        a1.v = xa[r & 1][1];
#pragma unroll
        for (int f = 0; f < 8; ++f) {
            const float sc = sc_lds[gl * 128 + f * 16 + nl];
            const float zs = zs_lds[gl * 128 + f * 16 + nl];
            const int4v p = *(const int4v*)(pwb + f * 4096 + boff);
            union { uint4 v; short8 sv; } bf;
            bf.v.x = dq2(p.x, sc, zs);
            bf.v.y = dq2(p.y, sc, zs);
            bf.v.z = dq2(p.z, sc, zs);
            bf.v.w = dq2(p.w, sc, zs);
            acc[f][0] = __builtin_amdgcn_mfma_f32_16x16x32_bf16(a0.sv, bf.sv, acc[f][0], 0, 0, 0);
            acc[f][1] = __builtin_amdgcn_mfma_f32_16x16x32_bf16(a1.sv, bf.sv, acc[f][1], 0, 0, 0);
        }
        __syncthreads();   // drains stage(r+1) (vmcnt 0) + finishes buf reads
    }

    // ---- epilogue: red overlays pwbuf/scz (all dead, all waves past barrier) ----
#pragma unroll
    for (int f = 0; f < 8; ++f)
#pragma unroll
        for (int mt = 0; mt < 2; ++mt)
#pragma unroll
            for (int rr = 0; rr < 4; ++rr)
                red[wave][mt * 16 + kq * 4 + rr][f * 16 + nl] = acc[f][mt][rr];
    __syncthreads();

#pragma unroll
    for (int j = 0; j < 16; ++j) {
        const int e = j * 256 + tid;      // 0..4095 partial elems
        const int m = e >> 7, c = e & 127;
        const float s = red[0][m][c] + red[1][m][c] + red[2][m][c] + red[3][m][c];
        atomicAdd(out + (size_t)m * NN + n0 + c, s);
    }
}

// Fallback (no workspace): register-path kernel, direct fp32 x loads, atomics.
__global__ __launch_bounds__(256, 4)
void gptq_mfma_fallback(const int*   __restrict__ pw,
                        const float* __restrict__ scales,
                        const float* __restrict__ zeros,
                        const float* __restrict__ x,
                        float* __restrict__ out)
{
    __shared__ float s_lds[64][17];
    __shared__ float z_lds[64][17];
    __shared__ float red[4][2][256];

    const int tid  = threadIdx.x;
    const int lane = tid & 63;
    const int wave = tid >> 6;
    const int kh   = blockIdx.x & 1;
    const int n0   = (blockIdx.x >> 1) * 16;
    const int g0   = kh * 64;

    {
        const int r  = tid >> 4;
        const int gb = (tid & 15) * 4;
        const float4 s4 = *(const float4*)(scales + (size_t)(n0 + r) * NG + g0 + gb);
        const float4 z4 = *(const float4*)(zeros  + (size_t)(n0 + r) * NG + g0 + gb);
        s_lds[gb + 0][r] = s4.x; s_lds[gb + 1][r] = s4.y;
        s_lds[gb + 2][r] = s4.z; s_lds[gb + 3][r] = s4.w;
        z_lds[gb + 0][r] = z4.x; z_lds[gb + 1][r] = z4.y;
        z_lds[gb + 2][r] = z4.z; z_lds[gb + 3][r] = z4.w;
    }
    __syncthreads();

    const int nl = lane & 15;
    const int kq = lane >> 4;
    const int* pwp = pw + (size_t)(n0 + nl) * KP + kq * 4;
    const int ks0 = kh * 128 + wave * 32;

    auto load_xfrag = [&](int mt, int ks) -> uint4 {
        const float* src = x + (size_t)(nl + 16 * mt) * KK + ks * 32 + kq * 8;
        const float4 a = *(const float4*)(src);
        const float4 b = *(const float4*)(src + 4);
        return make_uint4(pack_bf16x2(a.x, a.y), pack_bf16x2(a.z, a.w),
                          pack_bf16x2(b.x, b.y), pack_bf16x2(b.z, b.w));
    };

    floatx4 acc0 = {0.f, 0.f, 0.f, 0.f};
    floatx4 acc1 = {0.f, 0.f, 0.f, 0.f};
    int4v pwb[4];
    uint4 x0b[4], x1b[4];

#pragma unroll
    for (int i = 0; i < 3; ++i) {
        const int ks = ks0 + i;
        pwb[i] = *(const int4v*)(pwp + ks * 16);
        x0b[i] = load_xfrag(0, ks);
        x1b[i] = load_xfrag(1, ks);
    }

#pragma unroll 4
    for (int i = 0; i < 32; ++i) {
        const int slot = i & 3;
        if (i + 3 < 32) {
            const int ks = ks0 + i + 3;
            const int ps = (i + 3) & 3;
            pwb[ps] = *(const int4v*)(pwp + ks * 16);
            x0b[ps] = load_xfrag(0, ks);
            x1b[ps] = load_xfrag(1, ks);
        }
        const int gl  = (wave * 32 + i) >> 1;
        const float sc = s_lds[gl][nl];
        const float zs = -z_lds[gl][nl] * sc;

        union { uint4 v; short8 sv; } bf, a0, a1;
        const int4v p = pwb[slot];
        bf.v.x = dq2(p.x, sc, zs);
        bf.v.y = dq2(p.y, sc, zs);
        bf.v.z = dq2(p.z, sc, zs);
        bf.v.w = dq2(p.w, sc, zs);
        a0.v = x0b[slot];
        a1.v = x1b[slot];
        acc0 = __builtin_amdgcn_mfma_f32_16x16x32_bf16(a0.sv, bf.sv, acc0, 0, 0, 0);
        acc1 = __builtin_amdgcn_mfma_f32_16x16x32_bf16(a1.sv, bf.sv, acc1, 0, 0, 0);
    }

#pragma unroll
    for (int r = 0; r < 4; ++r) {
        const int row = kq * 4 + r;
        red[wave][0][row * 16 + nl] = acc0[r];
        red[wave][1][row * 16 + nl] = acc1[r];
    }
    __syncthreads();

#pragma unroll
    for (int i = 0; i < 2; ++i) {
        const int e   = i * 256 + tid;
        const int mt  = e >> 8;
        const int idx = e & 255;
        const float s = red[0][mt][idx] + red[1][mt][idx] + red[2][mt][idx] + red[3][mt][idx];
        atomicAdd(out + (size_t)(mt * 16 + (idx >> 4)) * NN + n0 + (idx & 15), s);
    }
}

extern "C" void kernel_launch(void* const* d_in, const int* in_sizes, int n_in,
                              void* d_out, int out_size, void* d_ws, size_t ws_size,
                              hipStream_t stream) {
    const float* x      = (const float*)d_in[0];
    const int*   pw     = (const int*)  d_in[1];
    const float* scales = (const float*)d_in[2];
    const float* zeros  = (const float*)d_in[3];
    const float* bias   = (const float*)d_in[4];
    float* out = (float*)d_out;

    const size_t need = (size_t)32768 * 16;   // 512 KB of bf16 A-frags
    if (d_ws != nullptr && ws_size >= need) {
        ushort* xb = (ushort*)d_ws;
        prep_kernel<<<128 + 256, 256, 0, stream>>>(x, bias, xb, out, 128);
        gptq_mfma_main<<<(NN / BN) * KSPLIT, 256, 0, stream>>>(pw, scales, zeros, xb, out);
    } else {
        prep_kernel<<<256, 256, 0, stream>>>(x, bias, nullptr, out, 0);
        gptq_mfma_fallback<<<1024, 256, 0, stream>>>(pw, scales, zeros, x, out);
    }
}